// Round 10
// baseline (2904.695 us; speedup 1.0000x reference)
//
#include <hip/hip_runtime.h>
#include <stdint.h>

// ---------------------------------------------------------------------------
// FlatLinear: y = x @ W^T + bias, W = centroids[labels] (4096x4096, K=256 cb)
// M=8192, N=4096, K=4096.  fused prep (dequant W->bf16 + cast x->bf16), then
// MFMA GEMM.
// R10: R6 champion kernel (256x128 tile, BK=32, 8 waves 4x2, LDS 48 KiB
// 2-buf, vmcnt(0)+barrier per step, verified conflict-free swizzle) with
// __launch_bounds__(512,6): 6 waves/EU = 24 waves/CU = 3 blocks/CU (was 4 ->
// 2 blocks). More cross-block desync to hide the per-step drain (m114).
// Pre-passes fused into one kernel.
// ---------------------------------------------------------------------------

typedef __attribute__((ext_vector_type(8))) short  bf16x8;
typedef __attribute__((ext_vector_type(4))) float  f32x4;
typedef __attribute__((ext_vector_type(4))) int    i32x4;
typedef __attribute__((ext_vector_type(8))) ushort u16x8;
typedef __attribute__((ext_vector_type(4))) float  fvec4;

#define K_DIM 4096
#define N_DIM 4096
#define NSTEP (K_DIM / 32)   // 128 K-steps of BK=32

__device__ __forceinline__ ushort f2bf(float f) {
  uint32_t u = __float_as_uint(f);
  return (ushort)((u + 0x7fffu + ((u >> 16) & 1u)) >> 16);
}

__device__ __forceinline__ void async16(const ushort* g, ushort* l) {
  __builtin_amdgcn_global_load_lds(
      (const __attribute__((address_space(1))) void*)g,
      (__attribute__((address_space(3))) void*)l, 16, 0, 0);
}

// ---------------- fused prep: dequant W -> bf16 and cast x -> bf16 ----------
// blocks [0, half) handle W, [half, grid) handle x. Both memory-bound.
__global__ __launch_bounds__(256) void prep(const int* __restrict__ labels,
                                            const float* __restrict__ cent,
                                            ushort* __restrict__ wb, int wN,
                                            const float* __restrict__ x,
                                            ushort* __restrict__ xb, int xN) {
  __shared__ ushort cb[256];
  cb[threadIdx.x] = f2bf(cent[threadIdx.x]);
  __syncthreads();
  const int half = gridDim.x >> 1;
  if ((int)blockIdx.x < half) {
    const int stride = half * 256 * 8;
    for (int i = ((int)blockIdx.x * 256 + (int)threadIdx.x) * 8; i < wN;
         i += stride) {
      i32x4 l0 = *(const i32x4*)(labels + i);
      i32x4 l1 = *(const i32x4*)(labels + i + 4);
      u16x8 w;
      w[0] = cb[l0[0]]; w[1] = cb[l0[1]]; w[2] = cb[l0[2]]; w[3] = cb[l0[3]];
      w[4] = cb[l1[0]]; w[5] = cb[l1[1]]; w[6] = cb[l1[2]]; w[7] = cb[l1[3]];
      *(u16x8*)(wb + i) = w;
    }
  } else {
    const int stride = (gridDim.x - half) * 256 * 8;
    for (int i = (((int)blockIdx.x - half) * 256 + (int)threadIdx.x) * 8;
         i < xN; i += stride) {
      fvec4 a = *(const fvec4*)(x + i);
      fvec4 b = *(const fvec4*)(x + i + 4);
      u16x8 w;
      w[0] = f2bf(a[0]); w[1] = f2bf(a[1]); w[2] = f2bf(a[2]); w[3] = f2bf(a[3]);
      w[4] = f2bf(b[0]); w[5] = f2bf(b[1]); w[6] = f2bf(b[2]); w[7] = f2bf(b[3]);
      *(u16x8*)(xb + i) = w;
    }
  }
}

// --------------------------- 256x128-tile bf16 GEMM -------------------------
// C[M][N] = A[M][K] * B[N][K]^T + bias.
// Tile 256x128, BK=32, 512 threads = 8 waves (4M x 2N), wave out = 64x64.
// LDS per buffer: A [256][32] (8192 ushort) + B [128][32] (4096 ushort), x2.
// Staging: 3 async16/thread/step; wave-uniform LDS dest (HW adds lane*16B);
// source pre-swizzled unit ^= ((row>>1)&3); reads use the same XOR
// (measured 0 conflicts). Per step: frags(buf b), 16 MFMA, vmcnt(0),
// s_barrier. 3 blocks/CU desync hides the drain.
__global__ __launch_bounds__(512, 6) void gemm2(const ushort* __restrict__ A,
                                                const ushort* __restrict__ B,
                                                const float* __restrict__ bias,
                                                float* __restrict__ C) {
  __shared__ ushort As[2][8192];   // [buf][256 rows x 32]
  __shared__ ushort Bs[2][4096];   // [buf][128 rows x 32]

  const int tid  = threadIdx.x;
  const int wid  = tid >> 6;
  const int lane = tid & 63;
  const int wm = wid >> 1, wn = wid & 1;
  const int l15 = lane & 15;

  // bijective XCD-aware swizzle (m204)
  const int nwg = gridDim.x, bid = blockIdx.x;
  const int q = nwg >> 3, r = nwg & 7;
  const int xcd = bid & 7, sub = bid >> 3;
  const int swz = (xcd < r ? xcd * (q + 1) : r * (q + 1) + (xcd - r) * q) + sub;
  const int gn = N_DIM / 128;          // 32
  const int bm = swz / gn, bn = swz % gn;

  // ---- staging: thread tid loads unit tid of A-low (rows 0..127), unit tid
  // of A-high (rows 128..255, LDS elem 4096+), unit tid of B (rows 0..127).
  // unit = 8 ushorts; row = tid>>2; src elem pre-swizzled by ((row>>1)&3)<<3
  // (row+128 keeps the same swizzle: 128>>1 = 64 == 0 mod 4).
  const int srow = tid >> 2;
  const int seu  = ((tid & 3) * 8) ^ (((srow >> 1) & 3) << 3);
  const ushort* gA0 = A + (size_t)(bm * 256 + srow) * K_DIM + seu;
  const ushort* gA1 = gA0 + (size_t)128 * K_DIM;
  const ushort* gB  = B + (size_t)(bn * 128 + srow) * K_DIM + seu;
  const int wbase = wid * 512;  // wave-uniform LDS unit base (64 lanes x 8)

  // ---- fragment read offsets (read-side XOR matches store swizzle):
  //   unit = (lane>>4) ^ ((row>>1)&3), row = <mult of 16> + l15
  const int esw  = ((lane >> 4) * 8) ^ (((l15 >> 1) & 3) << 3);
  const int aOff = (wm * 64 + l15) * 32 + esw;
  const int bOff = (wn * 64 + l15) * 32 + esw;

  f32x4 acc[4][4];
#pragma unroll
  for (int i = 0; i < 4; ++i)
#pragma unroll
    for (int j = 0; j < 4; ++j) acc[i][j] = (f32x4){0.f, 0.f, 0.f, 0.f};

  bf16x8 af[4], bfr[4];

#define STAGE_(b, kt)                               \
  do {                                              \
    async16(gA0 + (kt), &As[b][wbase]);             \
    async16(gA1 + (kt), &As[b][4096 + wbase]);      \
    async16(gB + (kt), &Bs[b][wbase]);              \
  } while (0)
#define LDFRAG_(b)                                                   \
  do {                                                               \
    _Pragma("unroll") for (int m_ = 0; m_ < 4; ++m_)                 \
        af[m_] = *(const bf16x8*)&As[b][aOff + m_ * 512];            \
    _Pragma("unroll") for (int n_ = 0; n_ < 4; ++n_)                 \
        bfr[n_] = *(const bf16x8*)&Bs[b][bOff + n_ * 512];           \
  } while (0)
#define MM_()                                                        \
  do {                                                               \
    __builtin_amdgcn_s_setprio(1);                                   \
    _Pragma("unroll") for (int m_ = 0; m_ < 4; ++m_)                 \
        _Pragma("unroll") for (int n_ = 0; n_ < 4; ++n_)             \
            acc[m_][n_] = __builtin_amdgcn_mfma_f32_16x16x32_bf16(   \
                af[m_], bfr[n_], acc[m_][n_], 0, 0, 0);              \
    __builtin_amdgcn_s_setprio(0);                                   \
  } while (0)
#define VMW0 asm volatile("s_waitcnt vmcnt(0)" ::: "memory")
#define BAR  __builtin_amdgcn_s_barrier()

  // prologue: stage step 0 into buf 0
  STAGE_(0, 0);
  VMW0;
  BAR;

  // 127 pipelined steps: 63 x (buf0, buf1) + 1 x buf0; tail reads buf1.
  for (int t = 0; t < NSTEP - 2; t += 2) {
    STAGE_(1, (t + 1) * 32);
    LDFRAG_(0); MM_();
    VMW0; BAR;
    STAGE_(0, (t + 2) * 32);
    LDFRAG_(1); MM_();
    VMW0; BAR;
  }
  STAGE_(1, (NSTEP - 1) * 32);
  LDFRAG_(0); MM_();
  VMW0; BAR;
  LDFRAG_(1); MM_();

#undef STAGE_
#undef LDFRAG_
#undef MM_
#undef VMW0
#undef BAR

  // C write: C/D layout col = lane&15, row = (lane>>4)*4 + reg
  float bb[4];
#pragma unroll
  for (int n = 0; n < 4; ++n) bb[n] = bias[bn * 128 + wn * 64 + n * 16 + l15];

  float* Cp = C + (size_t)(bm * 256 + wm * 64) * N_DIM + bn * 128 + wn * 64;
  const int rbase = (lane >> 4) * 4;
#pragma unroll
  for (int mi = 0; mi < 4; ++mi)
#pragma unroll
    for (int rr = 0; rr < 4; ++rr) {
      float* cr = Cp + (size_t)(mi * 16 + rbase + rr) * N_DIM;
#pragma unroll
      for (int n = 0; n < 4; ++n)
        cr[n * 16 + l15] = acc[mi][n][rr] + bb[n];
    }
}

// --------------------------- naive fallback (ws too small) ------------------
__global__ void naive_kernel(const float* __restrict__ x,
                             const float* __restrict__ cent,
                             const int* __restrict__ labels,
                             const float* __restrict__ bias,
                             float* __restrict__ out, int M) {
  __shared__ float cb[256];
  if (threadIdx.x < 256) cb[threadIdx.x] = cent[threadIdx.x];
  __syncthreads();
  long o = (long)blockIdx.x * blockDim.x + threadIdx.x;
  if (o >= (long)M * N_DIM) return;
  int n = (int)(o % N_DIM);
  long m = o / N_DIM;
  const float* xr = x + m * K_DIM;
  const int* lr = labels + (long)n * K_DIM;
  float s = 0.f;
  for (int k = 0; k < K_DIM; ++k) s += xr[k] * cb[lr[k]];
  out[o] = s + bias[n];
}

// ---------------------------------------------------------------------------
extern "C" void kernel_launch(void* const* d_in, const int* in_sizes, int n_in,
                              void* d_out, int out_size, void* d_ws, size_t ws_size,
                              hipStream_t stream) {
  const float* x      = (const float*)d_in[0];
  const float* cent   = (const float*)d_in[1];
  const int*   labels = (const int*)d_in[2];
  const float* bias   = (const float*)d_in[3];
  float* out = (float*)d_out;

  const int xN = in_sizes[0];      // M*K
  const int M  = xN / K_DIM;       // 8192
  const int wN = in_sizes[2];      // N*K

  const size_t need = (size_t)wN * 2 + (size_t)xN * 2;  // 96 MB
  if (ws_size < need || (M % 256) != 0) {
    long total = (long)M * N_DIM;
    int blocks = (int)((total + 255) / 256);
    naive_kernel<<<blocks, 256, 0, stream>>>(x, cent, labels, bias, out, M);
    return;
  }

  ushort* wb = (ushort*)d_ws;      // [N][K] bf16
  ushort* xb = wb + (size_t)wN;    // [M][K] bf16

  prep<<<2048, 256, 0, stream>>>(labels, cent, wb, wN, x, xb, xN);

  const int grid = (M / 256) * (N_DIM / 128);  // 1024
  gemm2<<<grid, 512, 0, stream>>>(xb, wb, bias, out);
}

// Round 11
// 325.851 us; speedup vs baseline: 8.9142x; 8.9142x over previous
//
#include <hip/hip_runtime.h>
#include <stdint.h>

// ---------------------------------------------------------------------------
// FlatLinear: y = x @ W^T + bias, W = centroids[labels] (4096x4096, K=256 cb)
// M=8192, N=4096, K=4096.  fused prep (dequant W->bf16 + cast x->bf16), then
// MFMA GEMM.
// R11: revert R10's launch_bounds to (512,4) — (512,6) forced a ~85-reg
// budget and spilled the 64-reg accumulator to scratch (VGPR=40, 13 GB of
// scratch traffic, 2.9 ms). R6 champion GEMM restored (280 us, MfmaUtil 45%,
// 0 bank conflicts, 2 blocks/CU); fused prep kernel kept from R10.
// ---------------------------------------------------------------------------

typedef __attribute__((ext_vector_type(8))) short  bf16x8;
typedef __attribute__((ext_vector_type(4))) float  f32x4;
typedef __attribute__((ext_vector_type(4))) int    i32x4;
typedef __attribute__((ext_vector_type(8))) ushort u16x8;
typedef __attribute__((ext_vector_type(4))) float  fvec4;

#define K_DIM 4096
#define N_DIM 4096
#define NSTEP (K_DIM / 32)   // 128 K-steps of BK=32

__device__ __forceinline__ ushort f2bf(float f) {
  uint32_t u = __float_as_uint(f);
  return (ushort)((u + 0x7fffu + ((u >> 16) & 1u)) >> 16);
}

__device__ __forceinline__ void async16(const ushort* g, ushort* l) {
  __builtin_amdgcn_global_load_lds(
      (const __attribute__((address_space(1))) void*)g,
      (__attribute__((address_space(3))) void*)l, 16, 0, 0);
}

// ---------------- fused prep: dequant W -> bf16 and cast x -> bf16 ----------
// blocks [0, half) handle W, [half, grid) handle x. Both memory-bound.
__global__ __launch_bounds__(256) void prep(const int* __restrict__ labels,
                                            const float* __restrict__ cent,
                                            ushort* __restrict__ wb, int wN,
                                            const float* __restrict__ x,
                                            ushort* __restrict__ xb, int xN) {
  __shared__ ushort cb[256];
  cb[threadIdx.x] = f2bf(cent[threadIdx.x]);
  __syncthreads();
  const int half = gridDim.x >> 1;
  if ((int)blockIdx.x < half) {
    const int stride = half * 256 * 8;
    for (int i = ((int)blockIdx.x * 256 + (int)threadIdx.x) * 8; i < wN;
         i += stride) {
      i32x4 l0 = *(const i32x4*)(labels + i);
      i32x4 l1 = *(const i32x4*)(labels + i + 4);
      u16x8 w;
      w[0] = cb[l0[0]]; w[1] = cb[l0[1]]; w[2] = cb[l0[2]]; w[3] = cb[l0[3]];
      w[4] = cb[l1[0]]; w[5] = cb[l1[1]]; w[6] = cb[l1[2]]; w[7] = cb[l1[3]];
      *(u16x8*)(wb + i) = w;
    }
  } else {
    const int stride = (gridDim.x - half) * 256 * 8;
    for (int i = (((int)blockIdx.x - half) * 256 + (int)threadIdx.x) * 8;
         i < xN; i += stride) {
      fvec4 a = *(const fvec4*)(x + i);
      fvec4 b = *(const fvec4*)(x + i + 4);
      u16x8 w;
      w[0] = f2bf(a[0]); w[1] = f2bf(a[1]); w[2] = f2bf(a[2]); w[3] = f2bf(a[3]);
      w[4] = f2bf(b[0]); w[5] = f2bf(b[1]); w[6] = f2bf(b[2]); w[7] = f2bf(b[3]);
      *(u16x8*)(xb + i) = w;
    }
  }
}

// --------------------------- 256x128-tile bf16 GEMM -------------------------
// C[M][N] = A[M][K] * B[N][K]^T + bias.
// Tile 256x128, BK=32, 512 threads = 8 waves (4M x 2N), wave out = 64x64.
// LDS per buffer: A [256][32] (8192 ushort) + B [128][32] (4096 ushort), x2.
// Staging: 3 async16/thread/step; wave-uniform LDS dest (HW adds lane*16B);
// source pre-swizzled unit ^= ((row>>1)&3); reads use the same XOR
// (measured 0 conflicts). Per step: frags(buf b), 16 MFMA, vmcnt(0),
// s_barrier. 2 blocks/CU desync hides the drain.
__global__ __launch_bounds__(512, 4) void gemm2(const ushort* __restrict__ A,
                                                const ushort* __restrict__ B,
                                                const float* __restrict__ bias,
                                                float* __restrict__ C) {
  __shared__ ushort As[2][8192];   // [buf][256 rows x 32]
  __shared__ ushort Bs[2][4096];   // [buf][128 rows x 32]

  const int tid  = threadIdx.x;
  const int wid  = tid >> 6;
  const int lane = tid & 63;
  const int wm = wid >> 1, wn = wid & 1;
  const int l15 = lane & 15;

  // bijective XCD-aware swizzle (m204)
  const int nwg = gridDim.x, bid = blockIdx.x;
  const int q = nwg >> 3, r = nwg & 7;
  const int xcd = bid & 7, sub = bid >> 3;
  const int swz = (xcd < r ? xcd * (q + 1) : r * (q + 1) + (xcd - r) * q) + sub;
  const int gn = N_DIM / 128;          // 32
  const int bm = swz / gn, bn = swz % gn;

  // ---- staging: thread tid loads unit tid of A-low (rows 0..127), unit tid
  // of A-high (rows 128..255, LDS elem 4096+), unit tid of B (rows 0..127).
  // unit = 8 ushorts; row = tid>>2; src elem pre-swizzled by ((row>>1)&3)<<3
  // (row+128 keeps the same swizzle: 128>>1 = 64 == 0 mod 4).
  const int srow = tid >> 2;
  const int seu  = ((tid & 3) * 8) ^ (((srow >> 1) & 3) << 3);
  const ushort* gA0 = A + (size_t)(bm * 256 + srow) * K_DIM + seu;
  const ushort* gA1 = gA0 + (size_t)128 * K_DIM;
  const ushort* gB  = B + (size_t)(bn * 128 + srow) * K_DIM + seu;
  const int wbase = wid * 512;  // wave-uniform LDS unit base (64 lanes x 8)

  // ---- fragment read offsets (read-side XOR matches store swizzle):
  //   unit = (lane>>4) ^ ((row>>1)&3), row = <mult of 16> + l15
  const int esw  = ((lane >> 4) * 8) ^ (((l15 >> 1) & 3) << 3);
  const int aOff = (wm * 64 + l15) * 32 + esw;
  const int bOff = (wn * 64 + l15) * 32 + esw;

  f32x4 acc[4][4];
#pragma unroll
  for (int i = 0; i < 4; ++i)
#pragma unroll
    for (int j = 0; j < 4; ++j) acc[i][j] = (f32x4){0.f, 0.f, 0.f, 0.f};

  bf16x8 af[4], bfr[4];

#define STAGE_(b, kt)                               \
  do {                                              \
    async16(gA0 + (kt), &As[b][wbase]);             \
    async16(gA1 + (kt), &As[b][4096 + wbase]);      \
    async16(gB + (kt), &Bs[b][wbase]);              \
  } while (0)
#define LDFRAG_(b)                                                   \
  do {                                                               \
    _Pragma("unroll") for (int m_ = 0; m_ < 4; ++m_)                 \
        af[m_] = *(const bf16x8*)&As[b][aOff + m_ * 512];            \
    _Pragma("unroll") for (int n_ = 0; n_ < 4; ++n_)                 \
        bfr[n_] = *(const bf16x8*)&Bs[b][bOff + n_ * 512];           \
  } while (0)
#define MM_()                                                        \
  do {                                                               \
    __builtin_amdgcn_s_setprio(1);                                   \
    _Pragma("unroll") for (int m_ = 0; m_ < 4; ++m_)                 \
        _Pragma("unroll") for (int n_ = 0; n_ < 4; ++n_)             \
            acc[m_][n_] = __builtin_amdgcn_mfma_f32_16x16x32_bf16(   \
                af[m_], bfr[n_], acc[m_][n_], 0, 0, 0);              \
    __builtin_amdgcn_s_setprio(0);                                   \
  } while (0)
#define VMW0 asm volatile("s_waitcnt vmcnt(0)" ::: "memory")
#define BAR  __builtin_amdgcn_s_barrier()

  // prologue: stage step 0 into buf 0
  STAGE_(0, 0);
  VMW0;
  BAR;

  // 127 pipelined steps: 63 x (buf0, buf1) + 1 x buf0; tail reads buf1.
  for (int t = 0; t < NSTEP - 2; t += 2) {
    STAGE_(1, (t + 1) * 32);
    LDFRAG_(0); MM_();
    VMW0; BAR;
    STAGE_(0, (t + 2) * 32);
    LDFRAG_(1); MM_();
    VMW0; BAR;
  }
  STAGE_(1, (NSTEP - 1) * 32);
  LDFRAG_(0); MM_();
  VMW0; BAR;
  LDFRAG_(1); MM_();

#undef STAGE_
#undef LDFRAG_
#undef MM_
#undef VMW0
#undef BAR

  // C write: C/D layout col = lane&15, row = (lane>>4)*4 + reg
  float bb[4];
#pragma unroll
  for (int n = 0; n < 4; ++n) bb[n] = bias[bn * 128 + wn * 64 + n * 16 + l15];

  float* Cp = C + (size_t)(bm * 256 + wm * 64) * N_DIM + bn * 128 + wn * 64;
  const int rbase = (lane >> 4) * 4;
#pragma unroll
  for (int mi = 0; mi < 4; ++mi)
#pragma unroll
    for (int rr = 0; rr < 4; ++rr) {
      float* cr = Cp + (size_t)(mi * 16 + rbase + rr) * N_DIM;
#pragma unroll
      for (int n = 0; n < 4; ++n)
        cr[n * 16 + l15] = acc[mi][n][rr] + bb[n];
    }
}

// --------------------------- naive fallback (ws too small) ------------------
__global__ void naive_kernel(const float* __restrict__ x,
                             const float* __restrict__ cent,
                             const int* __restrict__ labels,
                             const float* __restrict__ bias,
                             float* __restrict__ out, int M) {
  __shared__ float cb[256];
  if (threadIdx.x < 256) cb[threadIdx.x] = cent[threadIdx.x];
  __syncthreads();
  long o = (long)blockIdx.x * blockDim.x + threadIdx.x;
  if (o >= (long)M * N_DIM) return;
  int n = (int)(o % N_DIM);
  long m = o / N_DIM;
  const float* xr = x + m * K_DIM;
  const int* lr = labels + (long)n * K_DIM;
  float s = 0.f;
  for (int k = 0; k < K_DIM; ++k) s += xr[k] * cb[lr[k]];
  out[o] = s + bias[n];
}

// ---------------------------------------------------------------------------
extern "C" void kernel_launch(void* const* d_in, const int* in_sizes, int n_in,
                              void* d_out, int out_size, void* d_ws, size_t ws_size,
                              hipStream_t stream) {
  const float* x      = (const float*)d_in[0];
  const float* cent   = (const float*)d_in[1];
  const int*   labels = (const int*)d_in[2];
  const float* bias   = (const float*)d_in[3];
  float* out = (float*)d_out;

  const int xN = in_sizes[0];      // M*K
  const int M  = xN / K_DIM;       // 8192
  const int wN = in_sizes[2];      // N*K

  const size_t need = (size_t)wN * 2 + (size_t)xN * 2;  // 96 MB
  if (ws_size < need || (M % 256) != 0) {
    long total = (long)M * N_DIM;
    int blocks = (int)((total + 255) / 256);
    naive_kernel<<<blocks, 256, 0, stream>>>(x, cent, labels, bias, out, M);
    return;
  }

  ushort* wb = (ushort*)d_ws;      // [N][K] bf16
  ushort* xb = wb + (size_t)wN;    // [M][K] bf16

  prep<<<2048, 256, 0, stream>>>(labels, cent, wb, wN, x, xb, xN);

  const int grid = (M / 256) * (N_DIM / 128);  // 1024
  gemm2<<<grid, 512, 0, stream>>>(xb, wb, bias, out);
}

// Round 12
// 320.248 us; speedup vs baseline: 9.0701x; 1.0175x over previous
//
#include <hip/hip_runtime.h>
#include <stdint.h>

// ---------------------------------------------------------------------------
// FlatLinear: y = x @ W^T + bias, W = centroids[labels] (4096x4096, K=256 cb)
// M=8192, N=4096, K=4096.  dequant W->bf16, cast x->bf16, then MFMA GEMM.
// R13: exact R6 champion restored (separate prep kernels, 256x128 tile,
// BK=32, 8 waves 4x2, LDS 48 KiB 2-buf, vmcnt(0)+barrier per step,
// conflict-free swizzle, 2 blocks/CU) + NON-TEMPORAL C stores: C is 131 MB
// write-once data that was evicting the 96 MB A/B working set from L2/L3
// (FETCH 302 MB = 3x unique inputs). NT keeps A/B cache-resident.
// ---------------------------------------------------------------------------

typedef __attribute__((ext_vector_type(8))) short  bf16x8;
typedef __attribute__((ext_vector_type(4))) float  f32x4;
typedef __attribute__((ext_vector_type(4))) int    i32x4;
typedef __attribute__((ext_vector_type(8))) ushort u16x8;
typedef __attribute__((ext_vector_type(4))) float  fvec4;

#define K_DIM 4096
#define N_DIM 4096
#define NSTEP (K_DIM / 32)   // 128 K-steps of BK=32

__device__ __forceinline__ ushort f2bf(float f) {
  uint32_t u = __float_as_uint(f);
  return (ushort)((u + 0x7fffu + ((u >> 16) & 1u)) >> 16);
}

__device__ __forceinline__ void async16(const ushort* g, ushort* l) {
  __builtin_amdgcn_global_load_lds(
      (const __attribute__((address_space(1))) void*)g,
      (__attribute__((address_space(3))) void*)l, 16, 0, 0);
}

// --------------------------- dequant: labels -> bf16 W ---------------------
__global__ __launch_bounds__(256) void dequant_w(const int* __restrict__ labels,
                                                 const float* __restrict__ cent,
                                                 ushort* __restrict__ wb, int n) {
  __shared__ ushort cb[256];
  cb[threadIdx.x] = f2bf(cent[threadIdx.x]);
  __syncthreads();
  const int stride = gridDim.x * 256 * 8;
  for (int i = ((int)blockIdx.x * 256 + (int)threadIdx.x) * 8; i < n; i += stride) {
    i32x4 l0 = *(const i32x4*)(labels + i);
    i32x4 l1 = *(const i32x4*)(labels + i + 4);
    u16x8 w;
    w[0] = cb[l0[0]]; w[1] = cb[l0[1]]; w[2] = cb[l0[2]]; w[3] = cb[l0[3]];
    w[4] = cb[l1[0]]; w[5] = cb[l1[1]]; w[6] = cb[l1[2]]; w[7] = cb[l1[3]];
    *(u16x8*)(wb + i) = w;
  }
}

// --------------------------- cast: x fp32 -> bf16 ---------------------------
__global__ __launch_bounds__(256) void cvt_x(const float* __restrict__ x,
                                             ushort* __restrict__ xb, int n) {
  const int stride = gridDim.x * 256 * 8;
  for (int i = ((int)blockIdx.x * 256 + (int)threadIdx.x) * 8; i < n; i += stride) {
    fvec4 a = *(const fvec4*)(x + i);
    fvec4 b = *(const fvec4*)(x + i + 4);
    u16x8 w;
    w[0] = f2bf(a[0]); w[1] = f2bf(a[1]); w[2] = f2bf(a[2]); w[3] = f2bf(a[3]);
    w[4] = f2bf(b[0]); w[5] = f2bf(b[1]); w[6] = f2bf(b[2]); w[7] = f2bf(b[3]);
    *(u16x8*)(xb + i) = w;
  }
}

// --------------------------- 256x128-tile bf16 GEMM -------------------------
// C[M][N] = A[M][K] * B[N][K]^T + bias.
// Tile 256x128, BK=32, 512 threads = 8 waves (4M x 2N), wave out = 64x64.
// LDS per buffer: A [256][32] (8192 ushort) + B [128][32] (4096 ushort), x2.
// Staging: 3 async16/thread/step; wave-uniform LDS dest (HW adds lane*16B);
// source pre-swizzled unit ^= ((row>>1)&3); reads use the same XOR
// (measured 0 conflicts). Per step: frags(buf b), 16 MFMA, vmcnt(0),
// s_barrier. 2 blocks/CU desync hides the drain. NT C-stores in epilogue.
__global__ __launch_bounds__(512, 4) void gemm2(const ushort* __restrict__ A,
                                                const ushort* __restrict__ B,
                                                const float* __restrict__ bias,
                                                float* __restrict__ C) {
  __shared__ ushort As[2][8192];   // [buf][256 rows x 32]
  __shared__ ushort Bs[2][4096];   // [buf][128 rows x 32]

  const int tid  = threadIdx.x;
  const int wid  = tid >> 6;
  const int lane = tid & 63;
  const int wm = wid >> 1, wn = wid & 1;
  const int l15 = lane & 15;

  // bijective XCD-aware swizzle (m204)
  const int nwg = gridDim.x, bid = blockIdx.x;
  const int q = nwg >> 3, r = nwg & 7;
  const int xcd = bid & 7, sub = bid >> 3;
  const int swz = (xcd < r ? xcd * (q + 1) : r * (q + 1) + (xcd - r) * q) + sub;
  const int gn = N_DIM / 128;          // 32
  const int bm = swz / gn, bn = swz % gn;

  // ---- staging: thread tid loads unit tid of A-low (rows 0..127), unit tid
  // of A-high (rows 128..255, LDS elem 4096+), unit tid of B (rows 0..127).
  // unit = 8 ushorts; row = tid>>2; src elem pre-swizzled by ((row>>1)&3)<<3
  // (row+128 keeps the same swizzle: 128>>1 = 64 == 0 mod 4).
  const int srow = tid >> 2;
  const int seu  = ((tid & 3) * 8) ^ (((srow >> 1) & 3) << 3);
  const ushort* gA0 = A + (size_t)(bm * 256 + srow) * K_DIM + seu;
  const ushort* gA1 = gA0 + (size_t)128 * K_DIM;
  const ushort* gB  = B + (size_t)(bn * 128 + srow) * K_DIM + seu;
  const int wbase = wid * 512;  // wave-uniform LDS unit base (64 lanes x 8)

  // ---- fragment read offsets (read-side XOR matches store swizzle):
  //   unit = (lane>>4) ^ ((row>>1)&3), row = <mult of 16> + l15
  const int esw  = ((lane >> 4) * 8) ^ (((l15 >> 1) & 3) << 3);
  const int aOff = (wm * 64 + l15) * 32 + esw;
  const int bOff = (wn * 64 + l15) * 32 + esw;

  f32x4 acc[4][4];
#pragma unroll
  for (int i = 0; i < 4; ++i)
#pragma unroll
    for (int j = 0; j < 4; ++j) acc[i][j] = (f32x4){0.f, 0.f, 0.f, 0.f};

  bf16x8 af[4], bfr[4];

#define STAGE_(b, kt)                               \
  do {                                              \
    async16(gA0 + (kt), &As[b][wbase]);             \
    async16(gA1 + (kt), &As[b][4096 + wbase]);      \
    async16(gB + (kt), &Bs[b][wbase]);              \
  } while (0)
#define LDFRAG_(b)                                                   \
  do {                                                               \
    _Pragma("unroll") for (int m_ = 0; m_ < 4; ++m_)                 \
        af[m_] = *(const bf16x8*)&As[b][aOff + m_ * 512];            \
    _Pragma("unroll") for (int n_ = 0; n_ < 4; ++n_)                 \
        bfr[n_] = *(const bf16x8*)&Bs[b][bOff + n_ * 512];           \
  } while (0)
#define MM_()                                                        \
  do {                                                               \
    __builtin_amdgcn_s_setprio(1);                                   \
    _Pragma("unroll") for (int m_ = 0; m_ < 4; ++m_)                 \
        _Pragma("unroll") for (int n_ = 0; n_ < 4; ++n_)             \
            acc[m_][n_] = __builtin_amdgcn_mfma_f32_16x16x32_bf16(   \
                af[m_], bfr[n_], acc[m_][n_], 0, 0, 0);              \
    __builtin_amdgcn_s_setprio(0);                                   \
  } while (0)
#define VMW0 asm volatile("s_waitcnt vmcnt(0)" ::: "memory")
#define BAR  __builtin_amdgcn_s_barrier()

  // prologue: stage step 0 into buf 0
  STAGE_(0, 0);
  VMW0;
  BAR;

  // 127 pipelined steps: 63 x (buf0, buf1) + 1 x buf0; tail reads buf1.
  for (int t = 0; t < NSTEP - 2; t += 2) {
    STAGE_(1, (t + 1) * 32);
    LDFRAG_(0); MM_();
    VMW0; BAR;
    STAGE_(0, (t + 2) * 32);
    LDFRAG_(1); MM_();
    VMW0; BAR;
  }
  STAGE_(1, (NSTEP - 1) * 32);
  LDFRAG_(0); MM_();
  VMW0; BAR;
  LDFRAG_(1); MM_();

#undef STAGE_
#undef LDFRAG_
#undef MM_
#undef VMW0
#undef BAR

  // C write: C/D layout col = lane&15, row = (lane>>4)*4 + reg.
  // Non-temporal: C is write-once, keep A/B panels resident in L2/L3.
  float bb[4];
#pragma unroll
  for (int n = 0; n < 4; ++n) bb[n] = bias[bn * 128 + wn * 64 + n * 16 + l15];

  float* Cp = C + (size_t)(bm * 256 + wm * 64) * N_DIM + bn * 128 + wn * 64;
  const int rbase = (lane >> 4) * 4;
#pragma unroll
  for (int mi = 0; mi < 4; ++mi)
#pragma unroll
    for (int rr = 0; rr < 4; ++rr) {
      float* cr = Cp + (size_t)(mi * 16 + rbase + rr) * N_DIM;
#pragma unroll
      for (int n = 0; n < 4; ++n)
        __builtin_nontemporal_store(acc[mi][n][rr] + bb[n],
                                    &cr[n * 16 + l15]);
    }
}

// --------------------------- naive fallback (ws too small) ------------------
__global__ void naive_kernel(const float* __restrict__ x,
                             const float* __restrict__ cent,
                             const int* __restrict__ labels,
                             const float* __restrict__ bias,
                             float* __restrict__ out, int M) {
  __shared__ float cb[256];
  if (threadIdx.x < 256) cb[threadIdx.x] = cent[threadIdx.x];
  __syncthreads();
  long o = (long)blockIdx.x * blockDim.x + threadIdx.x;
  if (o >= (long)M * N_DIM) return;
  int n = (int)(o % N_DIM);
  long m = o / N_DIM;
  const float* xr = x + m * K_DIM;
  const int* lr = labels + (long)n * K_DIM;
  float s = 0.f;
  for (int k = 0; k < K_DIM; ++k) s += xr[k] * cb[lr[k]];
  out[o] = s + bias[n];
}

// ---------------------------------------------------------------------------
extern "C" void kernel_launch(void* const* d_in, const int* in_sizes, int n_in,
                              void* d_out, int out_size, void* d_ws, size_t ws_size,
                              hipStream_t stream) {
  const float* x      = (const float*)d_in[0];
  const float* cent   = (const float*)d_in[1];
  const int*   labels = (const int*)d_in[2];
  const float* bias   = (const float*)d_in[3];
  float* out = (float*)d_out;

  const int xN = in_sizes[0];      // M*K
  const int M  = xN / K_DIM;       // 8192
  const int wN = in_sizes[2];      // N*K

  const size_t need = (size_t)wN * 2 + (size_t)xN * 2;  // 96 MB
  if (ws_size < need || (M % 256) != 0) {
    long total = (long)M * N_DIM;
    int blocks = (int)((total + 255) / 256);
    naive_kernel<<<blocks, 256, 0, stream>>>(x, cent, labels, bias, out, M);
    return;
  }

  ushort* wb = (ushort*)d_ws;      // [N][K] bf16
  ushort* xb = wb + (size_t)wN;    // [M][K] bf16

  dequant_w<<<2048, 256, 0, stream>>>(labels, cent, wb, wN);
  cvt_x<<<2048, 256, 0, stream>>>(x, xb, xN);

  const int grid = (M / 256) * (N_DIM / 128);  // 1024
  gemm2<<<grid, 512, 0, stream>>>(xb, wb, bias, out);
}